// Round 13
// baseline (423.103 us; speedup 1.0000x reference)
//
#include <hip/hip_runtime.h>
#include <cstddef>
#include <cstdint>

#define B_   2
#define C_   1024
#define N_   4096   // H*W
#define M_   8192   // B*N
#define K2_  2048   // 2C
#define E_   4
#define HE_  512

typedef float f32x4 __attribute__((ext_vector_type(4)));
typedef short bf16x8 __attribute__((ext_vector_type(8)));
typedef _Float16 f16x8 __attribute__((ext_vector_type(8)));
typedef unsigned short u16x8 __attribute__((ext_vector_type(8)));

#define WAITV(N) asm volatile("s_waitcnt vmcnt(" #N ")" ::: "memory")
#define SBAR     __builtin_amdgcn_sched_barrier(0)

static __device__ __forceinline__ unsigned short f2bf(float f) {
  unsigned int u = __float_as_uint(f);
  u = u + 0x7fffu + ((u >> 16) & 1u);
  return (unsigned short)(u >> 16);
}

// global -> LDS direct copy, 16B per lane. LDS dest is wave-uniform base;
// HW writes at dest + lane*16. Global src is per-lane.
static __device__ __forceinline__ void gl_lds16(const void* g, void* l) {
  __builtin_amdgcn_global_load_lds(
      (const __attribute__((address_space(1))) void*)(uintptr_t)g,
      (__attribute__((address_space(3))) void*)(unsigned)(uintptr_t)l,
      16, 0, 0);
}

// ---------------- kernel 2: SE dual-branch gate -> wts0 [B,C] ----------------
__global__ __launch_bounds__(256) void k_se_gate(const float* __restrict__ s,
                                                 const float* __restrict__ w1, const float* __restrict__ b1,
                                                 const float* __restrict__ wa, const float* __restrict__ ba,
                                                 const float* __restrict__ wb, const float* __restrict__ bbv,
                                                 float* __restrict__ wts0) {
  __shared__ float hid[2][64];
  const int t = threadIdx.x;
  if (t < 128) {
    const int b = t >> 6, r = t & 63;
    float acc = b1[r];
    const float* sp = s + b * C_;
    const float* wp = w1 + r * C_;
    for (int c = 0; c < C_; ++c) acc = fmaf(sp[c], wp[c], acc);
    hid[b][r] = fmaxf(acc, 0.f);
  }
  __syncthreads();
  for (int o = t; o < B_ * C_; o += 256) {
    const int b = o >> 10, c = o & 1023;
    float a = ba[c], bb = bbv[c];
    #pragma unroll 8
    for (int r = 0; r < 64; ++r) {
      const float h = hid[b][r];
      a  = fmaf(h, wa[c * 64 + r], a);
      bb = fmaf(h, wb[c * 64 + r], bb);
    }
    wts0[o] = 1.f / (1.f + expf(bb - a));
  }
}

// ---------------- prep: x,t -> a_hi,a_mid fp16; ALSO per-(b,c,nblk) partial sums ----------------
__global__ __launch_bounds__(256) void k_prep_act(const float* __restrict__ x,
                                                  const float* __restrict__ t,
                                                  _Float16* __restrict__ ah,
                                                  _Float16* __restrict__ am,
                                                  float* __restrict__ spart) {
  __shared__ float tile[64][65];
  const int c0 = blockIdx.x * 64, n0 = blockIdx.y * 64, b = blockIdx.z;
  const float* xb = x + (size_t)b * (C_ * N_);
  const float* tb = t + (size_t)b * (C_ * N_);
  _Float16* ahb = ah + (size_t)b * (N_ * (size_t)K2_);
  _Float16* amb = am + (size_t)b * (N_ * (size_t)K2_);
  const int tid = threadIdx.x;
  const int prow = tid >> 2, pseg = tid & 3;
  float psum = 0.f;
  #pragma unroll
  for (int srcsel = 0; srcsel < 2; ++srcsel) {
    const float* src = srcsel ? tb : xb;
    const int koff = srcsel ? C_ : 0;
    if (srcsel) __syncthreads();
    #pragma unroll
    for (int p = 0; p < 4; ++p) {
      const int f = tid + p * 256;
      const int cr = f >> 4, nq = f & 15;
      const float4 v = *(const float4*)(src + (size_t)(c0 + cr) * N_ + n0 + nq * 4);
      tile[cr][nq * 4 + 0] = v.x; tile[cr][nq * 4 + 1] = v.y;
      tile[cr][nq * 4 + 2] = v.z; tile[cr][nq * 4 + 3] = v.w;
    }
    __syncthreads();
    {
      float a = 0.f;
      #pragma unroll
      for (int u = 0; u < 16; ++u) a += tile[prow][pseg * 16 + u];
      psum += a;
    }
    #pragma unroll
    for (int p = 0; p < 2; ++p) {
      const int f = tid + p * 256;
      const int mr = f >> 3, kq = f & 7;
      f16x8 hv, mv;
      #pragma unroll
      for (int u = 0; u < 8; ++u) {
        const float v = tile[kq * 8 + u][mr] * 64.f;
        const _Float16 h = (_Float16)v;
        hv[u] = h;
        mv[u] = (_Float16)(v - (float)h);
      }
      const size_t off = (size_t)(n0 + mr) * K2_ + koff + c0 + kq * 8;
      *(f16x8*)(ahb + off) = hv;
      *(f16x8*)(amb + off) = mv;
    }
  }
  psum += __shfl_xor(psum, 1);
  psum += __shfl_xor(psum, 2);
  if (pseg == 0)
    spart[((size_t)(b * C_ + c0 + prow)) * 64 + blockIdx.y] = psum;
}

// ---------------- reduce2: spart [B*C][64] -> s = mean (deterministic) ----------------
__global__ __launch_bounds__(256) void k_reduce2(const float* __restrict__ spart,
                                                 float* __restrict__ s) {
  const int idx = blockIdx.x * 256 + threadIdx.x;
  const float* p = spart + (size_t)idx * 64;
  float acc = 0.f;
  #pragma unroll
  for (int j = 0; j < 64; ++j) acc += p[j];
  s[idx] = acc * (1.f / (float)N_);
}

// ---------------- prep: fc_w [1024][2048] f32 -> w_hi,w_mid fp16, scale 4096 ----------------
__global__ __launch_bounds__(256) void k_prep_fcw(const float* __restrict__ w,
                                                  _Float16* __restrict__ wh,
                                                  _Float16* __restrict__ wm) {
  const size_t i = ((size_t)blockIdx.x * 256 + threadIdx.x) * 8;
  const float4 v0 = *(const float4*)(w + i);
  const float4 v1 = *(const float4*)(w + i + 4);
  const float vv[8] = {v0.x, v0.y, v0.z, v0.w, v1.x, v1.y, v1.z, v1.w};
  f16x8 hv, mv;
  #pragma unroll
  for (int u = 0; u < 8; ++u) {
    const float sv = vv[u] * 4096.f;
    const _Float16 h = (_Float16)sv;
    hv[u] = h;
    mv[u] = (_Float16)(sv - (float)h);
  }
  *(f16x8*)(wh + i) = hv;
  *(f16x8*)(wm + i) = mv;
}

// ---------------- prep: generic f32 [R][Cc] -> bf16 transposed [Cc][R] per z-slice ----------------
__global__ __launch_bounds__(256) void k_prep_tr(const float* __restrict__ src, long long zs, int srs,
                                                 unsigned short* __restrict__ dst, long long zo, int drs) {
  __shared__ float tile[64][65];
  const int c0 = blockIdx.x * 64, r0 = blockIdx.y * 64, z = blockIdx.z;
  const float* s = src + (size_t)z * zs;
  unsigned short* d = dst + (size_t)z * zo;
  const int tid = threadIdx.x;
  #pragma unroll
  for (int p = 0; p < 4; ++p) {
    const int f = tid + p * 256;
    const int rr = f >> 4, cq = f & 15;
    const float4 v = *(const float4*)(s + (size_t)(r0 + rr) * srs + c0 + cq * 4);
    tile[rr][cq * 4 + 0] = v.x; tile[rr][cq * 4 + 1] = v.y;
    tile[rr][cq * 4 + 2] = v.z; tile[rr][cq * 4 + 3] = v.w;
  }
  __syncthreads();
  #pragma unroll
  for (int p = 0; p < 2; ++p) {
    const int f = tid + p * 256;
    const int cr = f >> 3, rq = f & 7;
    u16x8 o;
    #pragma unroll
    for (int u = 0; u < 8; ++u) o[u] = f2bf(tile[rq * 8 + u][cr]);
    *(u16x8*)(d + (size_t)(c0 + cr) * drs + r0 + rq * 8) = o;
  }
}

// ---------------- fc GEMM: y = relu((Ah+Am)@(Wh+Wm)^T * 2^-18), fp16 split-MFMA ----------------
// 256x128 tile, 8 waves (4M x 2N, wave-tile 64x64), BK=32, 3-buffer rotation,
// ONE barrier per K-step, counted vmcnt (never 0 mid-loop). LDS 144KB, grid 256.
__global__ __launch_bounds__(512, 2) void k_fc_mfma(const _Float16* __restrict__ Ah,
                                                    const _Float16* __restrict__ Am,
                                                    const _Float16* __restrict__ Bh,
                                                    const _Float16* __restrict__ Bm,
                                                    float* __restrict__ y) {
  // per buffer: Ah 16KB @0 | Am 16KB @16384 | Bh 8KB @32768 | Bm 8KB @40960
  // A region: chunk = kg*256 + row (kg = k-oct, row 0..255); B region: chunk = kg*128 + row
  __shared__ __align__(16) char lds[3][49152];
  const int tid = threadIdx.x, w = tid >> 6, l = tid & 63;
  const int flat = blockIdx.x + blockIdx.y * 8;            // 256 blocks
  const int swz = (flat & 7) * 32 + (flat >> 3);           // XCD-contiguous m-panels
  const int n0 = (swz & 7) * 128, m0 = (swz >> 3) * 256;
  const int wr = w >> 1, wc = w & 1, lg = l >> 4, lr = l & 15;
  f32x4 acc[4][4] = {};

  auto LDA = [&](char* bufb, const _Float16* src, int roff, int k0, int q) {
    const int chunk = q * 512 + tid;
    const int kg = chunk >> 8, row = chunk & 255;
    gl_lds16(src + (size_t)(m0 + row) * K2_ + k0 + kg * 8,
             bufb + roff + (q * 512 + w * 64) * 16);
  };
  auto LDB = [&](char* bufb, const _Float16* src, int roff, int k0) {
    const int kg = tid >> 7, row = tid & 127;
    gl_lds16(src + (size_t)(n0 + row) * K2_ + k0 + kg * 8,
             bufb + roff + (w * 64) * 16);
  };
  auto STAGE = [&](int buf, int k0) {   // 6 loads per lane
    char* b = &lds[buf][0];
    LDA(b, Ah, 0, k0, 0);
    LDA(b, Ah, 0, k0, 1);
    LDB(b, Bh, 32768, k0);
    LDB(b, Bm, 40960, k0);
    LDA(b, Am, 16384, k0, 0);
    LDA(b, Am, 16384, k0, 1);
  };

  STAGE(0, 0);
  STAGE(1, 32);
  for (int t = 0; t < 64; ++t) {
    const int cur = t % 3;
    if (t < 63) { WAITV(6); } else { WAITV(0); }   // stage t landed; t+1 still flying
    SBAR;
    __builtin_amdgcn_s_barrier();                  // all waves consumed buf[(t+2)%3] last iter
    if (t < 62) STAGE((t + 2) % 3, (t + 2) * 32);
    const char* bb = &lds[cur][0];
    f16x8 a_h[4], a_m[4], b_h[4], b_m[4];
    #pragma unroll
    for (int i = 0; i < 4; ++i) {
      const int off = (lg * 256 + wr * 64 + i * 16 + lr) * 16;
      a_h[i] = *(const f16x8*)(bb + off);
      a_m[i] = *(const f16x8*)(bb + 16384 + off);
    }
    #pragma unroll
    for (int j = 0; j < 4; ++j) {
      const int off = (lg * 128 + wc * 64 + j * 16 + lr) * 16;
      b_h[j] = *(const f16x8*)(bb + 32768 + off);
      b_m[j] = *(const f16x8*)(bb + 40960 + off);
    }
    __builtin_amdgcn_s_setprio(1);
    #pragma unroll
    for (int i = 0; i < 4; ++i)
      #pragma unroll
      for (int j = 0; j < 4; ++j)
        acc[i][j] = __builtin_amdgcn_mfma_f32_16x16x32_f16(a_h[i], b_h[j], acc[i][j], 0, 0, 0);
    #pragma unroll
    for (int i = 0; i < 4; ++i)
      #pragma unroll
      for (int j = 0; j < 4; ++j)
        acc[i][j] = __builtin_amdgcn_mfma_f32_16x16x32_f16(a_h[i], b_m[j], acc[i][j], 0, 0, 0);
    #pragma unroll
    for (int i = 0; i < 4; ++i)
      #pragma unroll
      for (int j = 0; j < 4; ++j)
        acc[i][j] = __builtin_amdgcn_mfma_f32_16x16x32_f16(a_m[i], b_h[j], acc[i][j], 0, 0, 0);
    __builtin_amdgcn_s_setprio(0);
  }
  #pragma unroll
  for (int i = 0; i < 4; ++i) {
    const int mb = m0 + wr * 64 + i * 16 + lg * 4;
    #pragma unroll
    for (int j = 0; j < 4; ++j) {
      const int n = n0 + wc * 64 + j * 16 + lr;
      #pragma unroll
      for (int r = 0; r < 4; ++r)
        y[(size_t)(mb + r) * C_ + n] = fmaxf(acc[i][j][r] * (1.f / 262144.f), 0.f);
    }
  }
}

// ---------------- LayerNorm + logits + top-2 gates; writes yf bf16 ----------------
__global__ __launch_bounds__(256) void k_ln_topk(const float* __restrict__ y,
                                                 const float* __restrict__ lng, const float* __restrict__ lnb,
                                                 const float* __restrict__ wg, const int* __restrict__ taskp,
                                                 unsigned short* __restrict__ yf, float* __restrict__ gates) {
  const int wv = threadIdx.x >> 6, ln = threadIdx.x & 63;
  const int m = blockIdx.x * 4 + wv;
  const float* yr = y + (size_t)m * C_;
  float4 v[4];
  #pragma unroll
  for (int ch = 0; ch < 4; ++ch) v[ch] = *(const float4*)(yr + ch * 256 + ln * 4);
  float sum = 0.f;
  #pragma unroll
  for (int ch = 0; ch < 4; ++ch) sum += (v[ch].x + v[ch].y) + (v[ch].z + v[ch].w);
  #pragma unroll
  for (int o = 32; o; o >>= 1) sum += __shfl_down(sum, o);
  sum = __shfl(sum, 0);
  const float mu = sum * (1.f / 1024.f);
  float q = 0.f;
  #pragma unroll
  for (int ch = 0; ch < 4; ++ch) {
    const float dx = v[ch].x - mu, dy = v[ch].y - mu, dz = v[ch].z - mu, dw = v[ch].w - mu;
    q += (dx * dx + dy * dy) + (dz * dz + dw * dw);
  }
  #pragma unroll
  for (int o = 32; o; o >>= 1) q += __shfl_down(q, o);
  q = __shfl(q, 0);
  const float rstd = rsqrtf(q * (1.f / 1024.f) + 1e-5f);
  const float* wrow = wg + (size_t)(*taskp) * (C_ * E_);
  float l0 = 0.f, l1 = 0.f, l2 = 0.f, l3 = 0.f;
  #pragma unroll
  for (int ch = 0; ch < 4; ++ch) {
    const int c = ch * 256 + ln * 4;
    const float4 gg = *(const float4*)(lng + c);
    const float4 bv = *(const float4*)(lnb + c);
    float f[4];
    f[0] = (v[ch].x - mu) * rstd * gg.x + bv.x;
    f[1] = (v[ch].y - mu) * rstd * gg.y + bv.y;
    f[2] = (v[ch].z - mu) * rstd * gg.z + bv.z;
    f[3] = (v[ch].w - mu) * rstd * gg.w + bv.w;
    uint2 pk;
    pk.x = (unsigned)f2bf(f[0]) | ((unsigned)f2bf(f[1]) << 16);
    pk.y = (unsigned)f2bf(f[2]) | ((unsigned)f2bf(f[3]) << 16);
    *(uint2*)(yf + (size_t)m * C_ + c) = pk;
    #pragma unroll
    for (int i = 0; i < 4; ++i) {   // logits from pre-rounding f32 values
      const float4 we = *(const float4*)(wrow + (size_t)(c + i) * 4);
      l0 = fmaf(f[i], we.x, l0); l1 = fmaf(f[i], we.y, l1);
      l2 = fmaf(f[i], we.z, l2); l3 = fmaf(f[i], we.w, l3);
    }
  }
  #pragma unroll
  for (int o = 32; o; o >>= 1) {
    l0 += __shfl_down(l0, o); l1 += __shfl_down(l1, o);
    l2 += __shfl_down(l2, o); l3 += __shfl_down(l3, o);
  }
  if (ln == 0) {
    const float L[4] = {l0, l1, l2, l3};
    int i1 = 0; float best = L[0];
    #pragma unroll
    for (int e = 1; e < 4; ++e) if (L[e] > best) { best = L[e]; i1 = e; }
    int i2 = -1; float s2 = 0.f;
    #pragma unroll
    for (int e = 0; e < 4; ++e) if (e != i1 && (i2 < 0 || L[e] > s2)) { s2 = L[e]; i2 = e; }
    const float g1 = 1.f / (1.f + expf(s2 - best));
    const float g2 = 1.f - g1;
    float4 gv;
    gv.x = (i1 == 0) ? g1 : ((i2 == 0) ? g2 : 0.f);
    gv.y = (i1 == 1) ? g1 : ((i2 == 1) ? g2 : 0.f);
    gv.z = (i1 == 2) ? g1 : ((i2 == 2) ? g2 : 0.f);
    gv.w = (i1 == 3) ? g1 : ((i2 == 3) ? g2 : 0.f);
    *(float4*)(gates + (size_t)m * 4) = gv;
  }
}

// ---------------- moe1: ehg = gate * relu(yf @ w1t^T + b1), bf16 MFMA, 3-buf 1-barrier ----------------
__global__ __launch_bounds__(256) void k_moe1_mfma(const unsigned short* __restrict__ yf,
                                                   const short* __restrict__ Bw,
                                                   const float* __restrict__ b1,
                                                   const float* __restrict__ gates,
                                                   unsigned short* __restrict__ ehg) {
  __shared__ __align__(16) char lds[3][16384];   // [buf][A|B], 8KB each
  const int tid = threadIdx.x, w = tid >> 6, l = tid & 63;
  const int flat = blockIdx.x + blockIdx.y * 16;           // 1024 blocks
  const int swz = (flat & 7) * 128 + (flat >> 3);
  const int n0 = (swz & 15) * 128, m0 = (swz >> 4) * 128;
  const int wr = w >> 1, wc = w & 1, lg = l >> 4, lr = l & 15;
  f32x4 acc[4][4] = {};
  const int sg = tid >> 7, sr = tid & 127;
  const size_t ga0 = (size_t)(m0 + sr) * C_ + sg * 8;
  const size_t gb0 = (size_t)(n0 + sr) * C_ + sg * 8;

  auto STAGE = [&](int buf, int k0) {   // 4 loads per lane
    char* b = &lds[buf][0] + w * 1024;
    gl_lds16(yf + ga0 + k0, b);
    gl_lds16(yf + ga0 + 16 + k0, b + 4096);
    gl_lds16(Bw + gb0 + k0, b + 8192);
    gl_lds16(Bw + gb0 + 16 + k0, b + 12288);
  };

  STAGE(0, 0);
  STAGE(1, 32);
  for (int it = 0; it < 32; ++it) {
    const int cur = it % 3;
    if (it < 31) { WAITV(4); } else { WAITV(0); }
    SBAR;
    __builtin_amdgcn_s_barrier();
    if (it < 30) STAGE((it + 2) % 3, (it + 2) * 32);
    const char* bb = &lds[cur][0];
    bf16x8 af[4], bfr[4];
    #pragma unroll
    for (int i = 0; i < 4; ++i)
      af[i] = *(const bf16x8*)(bb + lg * 2048 + (wr * 64 + i * 16 + lr) * 16);
    #pragma unroll
    for (int j = 0; j < 4; ++j)
      bfr[j] = *(const bf16x8*)(bb + 8192 + lg * 2048 + (wc * 64 + j * 16 + lr) * 16);
    __builtin_amdgcn_s_setprio(1);
    #pragma unroll
    for (int i = 0; i < 4; ++i)
      #pragma unroll
      for (int j = 0; j < 4; ++j)
        acc[i][j] = __builtin_amdgcn_mfma_f32_16x16x32_bf16(af[i], bfr[j], acc[i][j], 0, 0, 0);
    __builtin_amdgcn_s_setprio(0);
  }
  const int e0 = n0 >> 9;
  #pragma unroll
  for (int j = 0; j < 4; ++j) {
    const int n = n0 + wc * 64 + j * 16 + lr;
    const float bias = b1[e0 * HE_ + (n & 511)];
    #pragma unroll
    for (int i = 0; i < 4; ++i) {
      const int mb = m0 + wr * 64 + i * 16 + lg * 4;
      #pragma unroll
      for (int r = 0; r < 4; ++r) {
        const float g = gates[(size_t)(mb + r) * 4 + e0];
        const float v = fmaxf(acc[i][j][r] + bias, 0.f) * g;
        ehg[(size_t)(mb + r) * K2_ + n] = f2bf(v);
      }
    }
  }
}

// ---------------- moe2: ym = ehg @ w2t^T + sum_e g*b2, bf16 MFMA, 3-buf 1-barrier ----------------
__global__ __launch_bounds__(256) void k_moe2_mfma(const short* __restrict__ Aeh,
                                                   const short* __restrict__ Bw,
                                                   const float* __restrict__ b2,
                                                   const float* __restrict__ gates,
                                                   float* __restrict__ ym) {
  __shared__ __align__(16) char lds[3][16384];
  const int tid = threadIdx.x, w = tid >> 6, l = tid & 63;
  const int flat = blockIdx.x + blockIdx.y * 8;            // 512 blocks
  const int swz = (flat & 7) * 64 + (flat >> 3);
  const int n0 = (swz & 7) * 128, m0 = (swz >> 3) * 128;
  const int wr = w >> 1, wc = w & 1, lg = l >> 4, lr = l & 15;
  f32x4 acc[4][4] = {};
  const int sg = tid >> 7, sr = tid & 127;
  const size_t ga0 = (size_t)(m0 + sr) * K2_ + sg * 8;
  const size_t gb0 = (size_t)(n0 + sr) * K2_ + sg * 8;

  auto STAGE = [&](int buf, int k0) {
    char* b = &lds[buf][0] + w * 1024;
    gl_lds16(Aeh + ga0 + k0, b);
    gl_lds16(Aeh + ga0 + 16 + k0, b + 4096);
    gl_lds16(Bw + gb0 + k0, b + 8192);
    gl_lds16(Bw + gb0 + 16 + k0, b + 12288);
  };

  STAGE(0, 0);
  STAGE(1, 32);
  for (int it = 0; it < 64; ++it) {
    const int cur = it % 3;
    if (it < 63) { WAITV(4); } else { WAITV(0); }
    SBAR;
    __builtin_amdgcn_s_barrier();
    if (it < 62) STAGE((it + 2) % 3, (it + 2) * 32);
    const char* bb = &lds[cur][0];
    bf16x8 af[4], bfr[4];
    #pragma unroll
    for (int i = 0; i < 4; ++i)
      af[i] = *(const bf16x8*)(bb + lg * 2048 + (wr * 64 + i * 16 + lr) * 16);
    #pragma unroll
    for (int j = 0; j < 4; ++j)
      bfr[j] = *(const bf16x8*)(bb + 8192 + lg * 2048 + (wc * 64 + j * 16 + lr) * 16);
    __builtin_amdgcn_s_setprio(1);
    #pragma unroll
    for (int i = 0; i < 4; ++i)
      #pragma unroll
      for (int j = 0; j < 4; ++j)
        acc[i][j] = __builtin_amdgcn_mfma_f32_16x16x32_bf16(af[i], bfr[j], acc[i][j], 0, 0, 0);
    __builtin_amdgcn_s_setprio(0);
  }
  float bb2[4][4];
  #pragma unroll
  for (int j = 0; j < 4; ++j) {
    const int n = n0 + wc * 64 + j * 16 + lr;
    #pragma unroll
    for (int e = 0; e < 4; ++e) bb2[j][e] = b2[e * C_ + n];
  }
  #pragma unroll
  for (int i = 0; i < 4; ++i) {
    const int mb = m0 + wr * 64 + i * 16 + lg * 4;
    #pragma unroll
    for (int r = 0; r < 4; ++r) {
      const float4 g = *(const float4*)(gates + (size_t)(mb + r) * 4);
      #pragma unroll
      for (int j = 0; j < 4; ++j) {
        const int n = n0 + wc * 64 + j * 16 + lr;
        ym[(size_t)(mb + r) * C_ + n] =
            acc[i][j][r] + g.x * bb2[j][0] + g.y * bb2[j][1] + g.z * bb2[j][2] + g.w * bb2[j][3];
      }
    }
  }
}

// ---------------- aux loss (deterministic single-block reduction) ----------------
__global__ __launch_bounds__(256) void k_aux(const float* __restrict__ gates, float* __restrict__ outp) {
  const int t = threadIdx.x;
  float imp[4] = {0, 0, 0, 0}, ld[4] = {0, 0, 0, 0};
  for (int m = t; m < M_; m += 256) {
    const float4 g = *(const float4*)(gates + (size_t)m * 4);
    imp[0] += g.x; imp[1] += g.y; imp[2] += g.z; imp[3] += g.w;
    ld[0] += (g.x > 0.f) ? 1.f : 0.f; ld[1] += (g.y > 0.f) ? 1.f : 0.f;
    ld[2] += (g.z > 0.f) ? 1.f : 0.f; ld[3] += (g.w > 0.f) ? 1.f : 0.f;
  }
  __shared__ float red[8][4];
  const int wv = t >> 6, ln = t & 63;
  #pragma unroll
  for (int e = 0; e < 4; ++e) {
    float a = imp[e], b = ld[e];
    #pragma unroll
    for (int o = 32; o; o >>= 1) { a += __shfl_down(a, o); b += __shfl_down(b, o); }
    if (ln == 0) { red[e][wv] = a; red[4 + e][wv] = b; }
  }
  __syncthreads();
  if (t == 0) {
    float I[4], L[4];
    #pragma unroll
    for (int e = 0; e < 4; ++e) {
      I[e] = red[e][0] + red[e][1] + red[e][2] + red[e][3];
      L[e] = red[4 + e][0] + red[4 + e][1] + red[4 + e][2] + red[4 + e][3];
    }
    const float mi = (I[0] + I[1] + I[2] + I[3]) * 0.25f;
    const float vi = ((I[0] - mi) * (I[0] - mi) + (I[1] - mi) * (I[1] - mi) +
                      (I[2] - mi) * (I[2] - mi) + (I[3] - mi) * (I[3] - mi)) / 3.f;
    const float ml = (L[0] + L[1] + L[2] + L[3]) * 0.25f;
    const float vl = ((L[0] - ml) * (L[0] - ml) + (L[1] - ml) * (L[1] - ml) +
                      (L[2] - ml) * (L[2] - ml) + (L[3] - ml) * (L[3] - ml)) / 3.f;
    *outp = vi / (mi * mi + 1e-10f) + vl / (ml * ml + 1e-10f);
  }
}

// ---------------- final: transpose ym [m,c]->[b,c,n], add z = w0*x+(1-w0)*t ----------------
__global__ __launch_bounds__(256) void k_final(const float* __restrict__ ym,
                                               const float* __restrict__ x, const float* __restrict__ t,
                                               const float* __restrict__ wts0, float* __restrict__ out) {
  __shared__ float tile[64][65];
  const int c0 = blockIdx.x * 64, n0 = blockIdx.y * 64, b = blockIdx.z;
  const int tid = threadIdx.x;
  #pragma unroll
  for (int p = 0; p < 4; ++p) {
    const int f = tid + p * 256;
    const int row = f >> 4, cq = f & 15;
    const float4 v = *(const float4*)(ym + (size_t)(b * N_ + n0 + row) * C_ + c0 + cq * 4);
    tile[row][cq * 4 + 0] = v.x; tile[row][cq * 4 + 1] = v.y;
    tile[row][cq * 4 + 2] = v.z; tile[row][cq * 4 + 3] = v.w;
  }
  __syncthreads();
  #pragma unroll
  for (int p = 0; p < 4; ++p) {
    const int f = tid + p * 256;
    const int cr = f >> 4, nq = f & 15;
    const int c = c0 + cr;
    const float w0 = wts0[b * C_ + c];
    const float w1 = 1.f - w0;
    const size_t idx = (size_t)(b * C_ + c) * N_ + n0 + nq * 4;
    const float4 xv = *(const float4*)(x + idx);
    const float4 tv = *(const float4*)(t + idx);
    float4 o;
    o.x = tile[nq * 4 + 0][cr] + w0 * xv.x + w1 * tv.x;
    o.y = tile[nq * 4 + 1][cr] + w0 * xv.y + w1 * tv.y;
    o.z = tile[nq * 4 + 2][cr] + w0 * xv.z + w1 * tv.z;
    o.w = tile[nq * 4 + 3][cr] + w0 * xv.w + w1 * tv.w;
    *(float4*)(out + idx) = o;
  }
}

extern "C" void kernel_launch(void* const* d_in, const int* in_sizes, int n_in,
                              void* d_out, int out_size, void* d_ws, size_t ws_size,
                              hipStream_t stream) {
  const float* x     = (const float*)d_in[0];
  const float* t     = (const float*)d_in[1];
  const float* fc_w  = (const float*)d_in[2];
  const float* ln_g  = (const float*)d_in[3];
  const float* ln_b  = (const float*)d_in[4];
  const float* f1_w1 = (const float*)d_in[5];
  const float* f1_b1 = (const float*)d_in[6];
  const float* f1_wa = (const float*)d_in[7];
  const float* f1_ba = (const float*)d_in[8];
  const float* f1_wb = (const float*)d_in[9];
  const float* f1_bb = (const float*)d_in[10];
  const float* w_gate = (const float*)d_in[11];
  const float* e_w1  = (const float*)d_in[12];
  const float* e_b1  = (const float*)d_in[13];
  const float* e_w2  = (const float*)d_in[14];
  const float* e_b2  = (const float*)d_in[15];
  const int*   task  = (const int*)d_in[16];
  float* out = (float*)d_out;

  char* ws = (char*)d_ws;
  float*          y     = (float*)ws;
  float*          spart = (float*)ws;                      // 512 KB, dead before fc
  _Float16*       ah    = (_Float16*)(ws + 33554432);
  _Float16*       am    = (_Float16*)(ws + 67108864);
  unsigned short* yf    = (unsigned short*)(ws + 33554432);
  unsigned short* ehg   = (unsigned short*)(ws + 50331648);
  _Float16* wh  = (_Float16*)(ws + 100663296);
  _Float16* wm  = (_Float16*)(ws + 104857600);
  short*    w1t = (short*)(ws + 109051904);
  short*    w2t = (short*)(ws + 113246208);
  float* sbuf  = (float*)(ws + 117440512);
  float* wts0  = (float*)(ws + 117448704);
  float* gates = (float*)(ws + 117456896);

  k_prep_fcw<<<1024, 256, 0, stream>>>(fc_w, wh, wm);
  k_prep_tr<<<dim3(8, 16, 4), 256, 0, stream>>>(e_w1, 524288LL, 512, (unsigned short*)w1t, 524288LL, 1024);
  k_prep_tr<<<dim3(16, 8, 4), 256, 0, stream>>>(e_w2, 524288LL, 1024, (unsigned short*)w2t, 512LL, 2048);
  k_prep_act<<<dim3(16, 64, 2), 256, 0, stream>>>(x, t, ah, am, spart);
  k_reduce2<<<8, 256, 0, stream>>>(spart, sbuf);
  k_se_gate<<<1, 256, 0, stream>>>(sbuf, f1_w1, f1_b1, f1_wa, f1_ba, f1_wb, f1_bb, wts0);
  k_fc_mfma<<<dim3(8, 32), 512, 0, stream>>>(ah, am, wh, wm, y);
  k_ln_topk<<<M_ / 4, 256, 0, stream>>>(y, ln_g, ln_b, w_gate, task, yf, gates);
  k_moe1_mfma<<<dim3(16, 64), 256, 0, stream>>>(yf, w1t, e_b1, gates, ehg);
  k_moe2_mfma<<<dim3(8, 64), 256, 0, stream>>>((const short*)ehg, w2t, e_b2, gates, y);
  k_aux<<<1, 256, 0, stream>>>(gates, out + (size_t)B_ * C_ * N_);
  k_final<<<dim3(C_ / 64, N_ / 64, B_), 256, 0, stream>>>(y, x, t, wts0, out);
}

// Round 14
// 406.915 us; speedup vs baseline: 1.0398x; 1.0398x over previous
//
#include <hip/hip_runtime.h>
#include <cstddef>
#include <cstdint>

#define B_   2
#define C_   1024
#define N_   4096   // H*W
#define M_   8192   // B*N
#define K2_  2048   // 2C
#define E_   4
#define HE_  512

typedef float f32x4 __attribute__((ext_vector_type(4)));
typedef short bf16x8 __attribute__((ext_vector_type(8)));
typedef _Float16 f16x8 __attribute__((ext_vector_type(8)));
typedef unsigned short u16x8 __attribute__((ext_vector_type(8)));

#define WAITV(N) asm volatile("s_waitcnt vmcnt(" #N ")" ::: "memory")
#define SBAR     __builtin_amdgcn_sched_barrier(0)

static __device__ __forceinline__ unsigned short f2bf(float f) {
  unsigned int u = __float_as_uint(f);
  u = u + 0x7fffu + ((u >> 16) & 1u);
  return (unsigned short)(u >> 16);
}

// global -> LDS direct copy, 16B per lane. LDS dest is wave-uniform base;
// HW writes at dest + lane*16. Global src is per-lane.
static __device__ __forceinline__ void gl_lds16(const void* g, void* l) {
  __builtin_amdgcn_global_load_lds(
      (const __attribute__((address_space(1))) void*)(uintptr_t)g,
      (__attribute__((address_space(3))) void*)(unsigned)(uintptr_t)l,
      16, 0, 0);
}

// ---------------- kernel 2: SE dual-branch gate -> wts0 [B,C] ----------------
__global__ __launch_bounds__(256) void k_se_gate(const float* __restrict__ s,
                                                 const float* __restrict__ w1, const float* __restrict__ b1,
                                                 const float* __restrict__ wa, const float* __restrict__ ba,
                                                 const float* __restrict__ wb, const float* __restrict__ bbv,
                                                 float* __restrict__ wts0) {
  __shared__ float hid[2][64];
  const int t = threadIdx.x;
  if (t < 128) {
    const int b = t >> 6, r = t & 63;
    float acc = b1[r];
    const float* sp = s + b * C_;
    const float* wp = w1 + r * C_;
    for (int c = 0; c < C_; ++c) acc = fmaf(sp[c], wp[c], acc);
    hid[b][r] = fmaxf(acc, 0.f);
  }
  __syncthreads();
  for (int o = t; o < B_ * C_; o += 256) {
    const int b = o >> 10, c = o & 1023;
    float a = ba[c], bb = bbv[c];
    #pragma unroll 8
    for (int r = 0; r < 64; ++r) {
      const float h = hid[b][r];
      a  = fmaf(h, wa[c * 64 + r], a);
      bb = fmaf(h, wb[c * 64 + r], bb);
    }
    wts0[o] = 1.f / (1.f + expf(bb - a));
  }
}

// ---------------- prep: x,t -> a_hi,a_mid fp16; ALSO per-(b,c,nblk) partial sums ----------------
__global__ __launch_bounds__(256) void k_prep_act(const float* __restrict__ x,
                                                  const float* __restrict__ t,
                                                  _Float16* __restrict__ ah,
                                                  _Float16* __restrict__ am,
                                                  float* __restrict__ spart) {
  __shared__ float tile[64][65];
  const int c0 = blockIdx.x * 64, n0 = blockIdx.y * 64, b = blockIdx.z;
  const float* xb = x + (size_t)b * (C_ * N_);
  const float* tb = t + (size_t)b * (C_ * N_);
  _Float16* ahb = ah + (size_t)b * (N_ * (size_t)K2_);
  _Float16* amb = am + (size_t)b * (N_ * (size_t)K2_);
  const int tid = threadIdx.x;
  const int prow = tid >> 2, pseg = tid & 3;
  float psum = 0.f;
  #pragma unroll
  for (int srcsel = 0; srcsel < 2; ++srcsel) {
    const float* src = srcsel ? tb : xb;
    const int koff = srcsel ? C_ : 0;
    if (srcsel) __syncthreads();
    #pragma unroll
    for (int p = 0; p < 4; ++p) {
      const int f = tid + p * 256;
      const int cr = f >> 4, nq = f & 15;
      const float4 v = *(const float4*)(src + (size_t)(c0 + cr) * N_ + n0 + nq * 4);
      tile[cr][nq * 4 + 0] = v.x; tile[cr][nq * 4 + 1] = v.y;
      tile[cr][nq * 4 + 2] = v.z; tile[cr][nq * 4 + 3] = v.w;
    }
    __syncthreads();
    {
      float a = 0.f;
      #pragma unroll
      for (int u = 0; u < 16; ++u) a += tile[prow][pseg * 16 + u];
      psum += a;
    }
    #pragma unroll
    for (int p = 0; p < 2; ++p) {
      const int f = tid + p * 256;
      const int mr = f >> 3, kq = f & 7;
      f16x8 hv, mv;
      #pragma unroll
      for (int u = 0; u < 8; ++u) {
        const float v = tile[kq * 8 + u][mr] * 64.f;
        const _Float16 h = (_Float16)v;
        hv[u] = h;
        mv[u] = (_Float16)(v - (float)h);
      }
      const size_t off = (size_t)(n0 + mr) * K2_ + koff + c0 + kq * 8;
      *(f16x8*)(ahb + off) = hv;
      *(f16x8*)(amb + off) = mv;
    }
  }
  psum += __shfl_xor(psum, 1);
  psum += __shfl_xor(psum, 2);
  if (pseg == 0)
    spart[((size_t)(b * C_ + c0 + prow)) * 64 + blockIdx.y] = psum;
}

// ---------------- reduce2: spart [B*C][64] -> s = mean (deterministic) ----------------
__global__ __launch_bounds__(256) void k_reduce2(const float* __restrict__ spart,
                                                 float* __restrict__ s) {
  const int idx = blockIdx.x * 256 + threadIdx.x;
  const float* p = spart + (size_t)idx * 64;
  float acc = 0.f;
  #pragma unroll
  for (int j = 0; j < 64; ++j) acc += p[j];
  s[idx] = acc * (1.f / (float)N_);
}

// ---------------- prep: fc_w [1024][2048] f32 -> w_hi,w_mid fp16, scale 4096 ----------------
__global__ __launch_bounds__(256) void k_prep_fcw(const float* __restrict__ w,
                                                  _Float16* __restrict__ wh,
                                                  _Float16* __restrict__ wm) {
  const size_t i = ((size_t)blockIdx.x * 256 + threadIdx.x) * 8;
  const float4 v0 = *(const float4*)(w + i);
  const float4 v1 = *(const float4*)(w + i + 4);
  const float vv[8] = {v0.x, v0.y, v0.z, v0.w, v1.x, v1.y, v1.z, v1.w};
  f16x8 hv, mv;
  #pragma unroll
  for (int u = 0; u < 8; ++u) {
    const float sv = vv[u] * 4096.f;
    const _Float16 h = (_Float16)sv;
    hv[u] = h;
    mv[u] = (_Float16)(sv - (float)h);
  }
  *(f16x8*)(wh + i) = hv;
  *(f16x8*)(wm + i) = mv;
}

// ---------------- prep: generic f32 [R][Cc] -> bf16 transposed [Cc][R] per z-slice ----------------
__global__ __launch_bounds__(256) void k_prep_tr(const float* __restrict__ src, long long zs, int srs,
                                                 unsigned short* __restrict__ dst, long long zo, int drs) {
  __shared__ float tile[64][65];
  const int c0 = blockIdx.x * 64, r0 = blockIdx.y * 64, z = blockIdx.z;
  const float* s = src + (size_t)z * zs;
  unsigned short* d = dst + (size_t)z * zo;
  const int tid = threadIdx.x;
  #pragma unroll
  for (int p = 0; p < 4; ++p) {
    const int f = tid + p * 256;
    const int rr = f >> 4, cq = f & 15;
    const float4 v = *(const float4*)(s + (size_t)(r0 + rr) * srs + c0 + cq * 4);
    tile[rr][cq * 4 + 0] = v.x; tile[rr][cq * 4 + 1] = v.y;
    tile[rr][cq * 4 + 2] = v.z; tile[rr][cq * 4 + 3] = v.w;
  }
  __syncthreads();
  #pragma unroll
  for (int p = 0; p < 2; ++p) {
    const int f = tid + p * 256;
    const int cr = f >> 3, rq = f & 7;
    u16x8 o;
    #pragma unroll
    for (int u = 0; u < 8; ++u) o[u] = f2bf(tile[rq * 8 + u][cr]);
    *(u16x8*)(d + (size_t)(c0 + cr) * drs + r0 + rq * 8) = o;
  }
}

// ---------------- fc GEMM: y = relu((Ah+Am)@(Wh+Wm)^T * 2^-18), fp16 split-MFMA ----------------
// 256x128 tile, 8 waves (4M x 2N, wave-tile 64x64), BK=32, 3-phase term-pipelined schedule,
// derived per-phase counted vmcnt (never 0 mid-loop), grid 256 = 1 block/CU, LDS 96KB. (r12 proven)
__global__ __launch_bounds__(512, 2) void k_fc_mfma(const _Float16* __restrict__ Ah,
                                                    const _Float16* __restrict__ Am,
                                                    const _Float16* __restrict__ Bh,
                                                    const _Float16* __restrict__ Bm,
                                                    float* __restrict__ y) {
  // per buffer: Ah 16KB @0 | Am 16KB @16384 | Bh 8KB @32768 | Bm 8KB @40960
  __shared__ __align__(16) char lds[2][49152];
  const int tid = threadIdx.x, w = tid >> 6, l = tid & 63;
  const int flat = blockIdx.x + blockIdx.y * 8;            // 256 blocks
  const int swz = (flat & 7) * 32 + (flat >> 3);           // XCD-contiguous m-panels
  const int n0 = (swz & 7) * 128, m0 = (swz >> 3) * 256;
  const int wr = w >> 1, wc = w & 1, lg = l >> 4, lr = l & 15;
  f32x4 acc[4][4] = {};

  auto LDA = [&](char* bufb, const _Float16* src, int roff, int k0, int q) {
    const int chunk = q * 512 + tid;
    const int kg = chunk >> 8, row = chunk & 255;
    gl_lds16(src + (size_t)(m0 + row) * K2_ + k0 + kg * 8,
             bufb + roff + (q * 512 + w * 64) * 16);
  };
  auto LDB = [&](char* bufb, const _Float16* src, int roff, int k0) {
    const int kg = tid >> 7, row = tid & 127;
    gl_lds16(src + (size_t)(n0 + row) * K2_ + k0 + kg * 8,
             bufb + roff + (w * 64) * 16);
  };

  // prologue: tile 0 -> buf0, issue order Ah,Ah,Bh,Bm,Am,Am
  LDA(&lds[0][0], Ah, 0, 0, 0);
  LDA(&lds[0][0], Ah, 0, 0, 1);
  LDB(&lds[0][0], Bh, 32768, 0);
  LDB(&lds[0][0], Bm, 40960, 0);
  LDA(&lds[0][0], Am, 16384, 0, 0);
  LDA(&lds[0][0], Am, 16384, 0, 1);

  f16x8 a_h[4], b_h[4], b_m[4], a_m[4];
  for (int t = 0; t < 63; ++t) {
    const int cur = t & 1;
    const char* bb = &lds[cur][0];
    char* nb = &lds[cur ^ 1][0];
    const int nk = (t + 1) * 32;
    // ---- phase 0: hh ----
    WAITV(3); SBAR;
    __builtin_amdgcn_s_barrier();
    LDA(nb, Ah, 0, nk, 0);
    LDA(nb, Ah, 0, nk, 1);
    #pragma unroll
    for (int i = 0; i < 4; ++i)
      a_h[i] = *(const f16x8*)(bb + (lg * 256 + wr * 64 + i * 16 + lr) * 16);
    #pragma unroll
    for (int j = 0; j < 4; ++j)
      b_h[j] = *(const f16x8*)(bb + 32768 + (lg * 128 + wc * 64 + j * 16 + lr) * 16);
    __builtin_amdgcn_s_setprio(1);
    #pragma unroll
    for (int i = 0; i < 4; ++i)
      #pragma unroll
      for (int j = 0; j < 4; ++j)
        acc[i][j] = __builtin_amdgcn_mfma_f32_16x16x32_f16(a_h[i], b_h[j], acc[i][j], 0, 0, 0);
    __builtin_amdgcn_s_setprio(0);
    // ---- phase 1: hm ----
    WAITV(4); SBAR;
    __builtin_amdgcn_s_barrier();
    LDB(nb, Bh, 32768, nk);
    LDB(nb, Bm, 40960, nk);
    #pragma unroll
    for (int j = 0; j < 4; ++j)
      b_m[j] = *(const f16x8*)(bb + 40960 + (lg * 128 + wc * 64 + j * 16 + lr) * 16);
    __builtin_amdgcn_s_setprio(1);
    #pragma unroll
    for (int i = 0; i < 4; ++i)
      #pragma unroll
      for (int j = 0; j < 4; ++j)
        acc[i][j] = __builtin_amdgcn_mfma_f32_16x16x32_f16(a_h[i], b_m[j], acc[i][j], 0, 0, 0);
    __builtin_amdgcn_s_setprio(0);
    // ---- phase 2: mh ----
    WAITV(4); SBAR;
    __builtin_amdgcn_s_barrier();
    LDA(nb, Am, 16384, nk, 0);
    LDA(nb, Am, 16384, nk, 1);
    #pragma unroll
    for (int i = 0; i < 4; ++i)
      a_m[i] = *(const f16x8*)(bb + 16384 + (lg * 256 + wr * 64 + i * 16 + lr) * 16);
    __builtin_amdgcn_s_setprio(1);
    #pragma unroll
    for (int i = 0; i < 4; ++i)
      #pragma unroll
      for (int j = 0; j < 4; ++j)
        acc[i][j] = __builtin_amdgcn_mfma_f32_16x16x32_f16(a_m[i], b_h[j], acc[i][j], 0, 0, 0);
    __builtin_amdgcn_s_setprio(0);
  }
  {  // tail tile t=63
    const char* bb = &lds[1][0];
    WAITV(3); SBAR;
    __builtin_amdgcn_s_barrier();
    #pragma unroll
    for (int i = 0; i < 4; ++i)
      a_h[i] = *(const f16x8*)(bb + (lg * 256 + wr * 64 + i * 16 + lr) * 16);
    #pragma unroll
    for (int j = 0; j < 4; ++j)
      b_h[j] = *(const f16x8*)(bb + 32768 + (lg * 128 + wc * 64 + j * 16 + lr) * 16);
    #pragma unroll
    for (int i = 0; i < 4; ++i)
      #pragma unroll
      for (int j = 0; j < 4; ++j)
        acc[i][j] = __builtin_amdgcn_mfma_f32_16x16x32_f16(a_h[i], b_h[j], acc[i][j], 0, 0, 0);
    WAITV(2); SBAR;
    __builtin_amdgcn_s_barrier();
    #pragma unroll
    for (int j = 0; j < 4; ++j)
      b_m[j] = *(const f16x8*)(bb + 40960 + (lg * 128 + wc * 64 + j * 16 + lr) * 16);
    #pragma unroll
    for (int i = 0; i < 4; ++i)
      #pragma unroll
      for (int j = 0; j < 4; ++j)
        acc[i][j] = __builtin_amdgcn_mfma_f32_16x16x32_f16(a_h[i], b_m[j], acc[i][j], 0, 0, 0);
    WAITV(0); SBAR;
    __builtin_amdgcn_s_barrier();
    #pragma unroll
    for (int i = 0; i < 4; ++i)
      a_m[i] = *(const f16x8*)(bb + 16384 + (lg * 256 + wr * 64 + i * 16 + lr) * 16);
    #pragma unroll
    for (int i = 0; i < 4; ++i)
      #pragma unroll
      for (int j = 0; j < 4; ++j)
        acc[i][j] = __builtin_amdgcn_mfma_f32_16x16x32_f16(a_m[i], b_h[j], acc[i][j], 0, 0, 0);
  }
  #pragma unroll
  for (int i = 0; i < 4; ++i) {
    const int mb = m0 + wr * 64 + i * 16 + lg * 4;
    #pragma unroll
    for (int j = 0; j < 4; ++j) {
      const int n = n0 + wc * 64 + j * 16 + lr;
      #pragma unroll
      for (int r = 0; r < 4; ++r)
        y[(size_t)(mb + r) * C_ + n] = fmaxf(acc[i][j][r] * (1.f / 262144.f), 0.f);
    }
  }
}

// ---------------- LayerNorm + logits + top-2 gates; writes yf bf16 ----------------
__global__ __launch_bounds__(256) void k_ln_topk(const float* __restrict__ y,
                                                 const float* __restrict__ lng, const float* __restrict__ lnb,
                                                 const float* __restrict__ wg, const int* __restrict__ taskp,
                                                 unsigned short* __restrict__ yf, float* __restrict__ gates) {
  const int wv = threadIdx.x >> 6, ln = threadIdx.x & 63;
  const int m = blockIdx.x * 4 + wv;
  const float* yr = y + (size_t)m * C_;
  float4 v[4];
  #pragma unroll
  for (int ch = 0; ch < 4; ++ch) v[ch] = *(const float4*)(yr + ch * 256 + ln * 4);
  float sum = 0.f;
  #pragma unroll
  for (int ch = 0; ch < 4; ++ch) sum += (v[ch].x + v[ch].y) + (v[ch].z + v[ch].w);
  #pragma unroll
  for (int o = 32; o; o >>= 1) sum += __shfl_down(sum, o);
  sum = __shfl(sum, 0);
  const float mu = sum * (1.f / 1024.f);
  float q = 0.f;
  #pragma unroll
  for (int ch = 0; ch < 4; ++ch) {
    const float dx = v[ch].x - mu, dy = v[ch].y - mu, dz = v[ch].z - mu, dw = v[ch].w - mu;
    q += (dx * dx + dy * dy) + (dz * dz + dw * dw);
  }
  #pragma unroll
  for (int o = 32; o; o >>= 1) q += __shfl_down(q, o);
  q = __shfl(q, 0);
  const float rstd = rsqrtf(q * (1.f / 1024.f) + 1e-5f);
  const float* wrow = wg + (size_t)(*taskp) * (C_ * E_);
  float l0 = 0.f, l1 = 0.f, l2 = 0.f, l3 = 0.f;
  #pragma unroll
  for (int ch = 0; ch < 4; ++ch) {
    const int c = ch * 256 + ln * 4;
    const float4 gg = *(const float4*)(lng + c);
    const float4 bv = *(const float4*)(lnb + c);
    float f[4];
    f[0] = (v[ch].x - mu) * rstd * gg.x + bv.x;
    f[1] = (v[ch].y - mu) * rstd * gg.y + bv.y;
    f[2] = (v[ch].z - mu) * rstd * gg.z + bv.z;
    f[3] = (v[ch].w - mu) * rstd * gg.w + bv.w;
    uint2 pk;
    pk.x = (unsigned)f2bf(f[0]) | ((unsigned)f2bf(f[1]) << 16);
    pk.y = (unsigned)f2bf(f[2]) | ((unsigned)f2bf(f[3]) << 16);
    *(uint2*)(yf + (size_t)m * C_ + c) = pk;
    #pragma unroll
    for (int i = 0; i < 4; ++i) {   // logits from pre-rounding f32 values
      const float4 we = *(const float4*)(wrow + (size_t)(c + i) * 4);
      l0 = fmaf(f[i], we.x, l0); l1 = fmaf(f[i], we.y, l1);
      l2 = fmaf(f[i], we.z, l2); l3 = fmaf(f[i], we.w, l3);
    }
  }
  #pragma unroll
  for (int o = 32; o; o >>= 1) {
    l0 += __shfl_down(l0, o); l1 += __shfl_down(l1, o);
    l2 += __shfl_down(l2, o); l3 += __shfl_down(l3, o);
  }
  if (ln == 0) {
    const float L[4] = {l0, l1, l2, l3};
    int i1 = 0; float best = L[0];
    #pragma unroll
    for (int e = 1; e < 4; ++e) if (L[e] > best) { best = L[e]; i1 = e; }
    int i2 = -1; float s2 = 0.f;
    #pragma unroll
    for (int e = 0; e < 4; ++e) if (e != i1 && (i2 < 0 || L[e] > s2)) { s2 = L[e]; i2 = e; }
    const float g1 = 1.f / (1.f + expf(s2 - best));
    const float g2 = 1.f - g1;
    float4 gv;
    gv.x = (i1 == 0) ? g1 : ((i2 == 0) ? g2 : 0.f);
    gv.y = (i1 == 1) ? g1 : ((i2 == 1) ? g2 : 0.f);
    gv.z = (i1 == 2) ? g1 : ((i2 == 2) ? g2 : 0.f);
    gv.w = (i1 == 3) ? g1 : ((i2 == 3) ? g2 : 0.f);
    *(float4*)(gates + (size_t)m * 4) = gv;
  }
}

// ---------------- moe1: ehg = gate * relu(yf @ w1t^T + b1), bf16 MFMA, 3-buf 1-barrier (r13) ----------------
__global__ __launch_bounds__(256) void k_moe1_mfma(const unsigned short* __restrict__ yf,
                                                   const short* __restrict__ Bw,
                                                   const float* __restrict__ b1,
                                                   const float* __restrict__ gates,
                                                   unsigned short* __restrict__ ehg) {
  __shared__ __align__(16) char lds[3][16384];   // [buf][A|B], 8KB each
  const int tid = threadIdx.x, w = tid >> 6, l = tid & 63;
  const int flat = blockIdx.x + blockIdx.y * 16;           // 1024 blocks
  const int swz = (flat & 7) * 128 + (flat >> 3);
  const int n0 = (swz & 15) * 128, m0 = (swz >> 4) * 128;
  const int wr = w >> 1, wc = w & 1, lg = l >> 4, lr = l & 15;
  f32x4 acc[4][4] = {};
  const int sg = tid >> 7, sr = tid & 127;
  const size_t ga0 = (size_t)(m0 + sr) * C_ + sg * 8;
  const size_t gb0 = (size_t)(n0 + sr) * C_ + sg * 8;

  auto STAGE = [&](int buf, int k0) {   // 4 loads per lane
    char* b = &lds[buf][0] + w * 1024;
    gl_lds16(yf + ga0 + k0, b);
    gl_lds16(yf + ga0 + 16 + k0, b + 4096);
    gl_lds16(Bw + gb0 + k0, b + 8192);
    gl_lds16(Bw + gb0 + 16 + k0, b + 12288);
  };

  STAGE(0, 0);
  STAGE(1, 32);
  for (int it = 0; it < 32; ++it) {
    const int cur = it % 3;
    if (it < 31) { WAITV(4); } else { WAITV(0); }
    SBAR;
    __builtin_amdgcn_s_barrier();
    if (it < 30) STAGE((it + 2) % 3, (it + 2) * 32);
    const char* bb = &lds[cur][0];
    bf16x8 af[4], bfr[4];
    #pragma unroll
    for (int i = 0; i < 4; ++i)
      af[i] = *(const bf16x8*)(bb + lg * 2048 + (wr * 64 + i * 16 + lr) * 16);
    #pragma unroll
    for (int j = 0; j < 4; ++j)
      bfr[j] = *(const bf16x8*)(bb + 8192 + lg * 2048 + (wc * 64 + j * 16 + lr) * 16);
    __builtin_amdgcn_s_setprio(1);
    #pragma unroll
    for (int i = 0; i < 4; ++i)
      #pragma unroll
      for (int j = 0; j < 4; ++j)
        acc[i][j] = __builtin_amdgcn_mfma_f32_16x16x32_bf16(af[i], bfr[j], acc[i][j], 0, 0, 0);
    __builtin_amdgcn_s_setprio(0);
  }
  const int e0 = n0 >> 9;
  #pragma unroll
  for (int j = 0; j < 4; ++j) {
    const int n = n0 + wc * 64 + j * 16 + lr;
    const float bias = b1[e0 * HE_ + (n & 511)];
    #pragma unroll
    for (int i = 0; i < 4; ++i) {
      const int mb = m0 + wr * 64 + i * 16 + lg * 4;
      #pragma unroll
      for (int r = 0; r < 4; ++r) {
        const float g = gates[(size_t)(mb + r) * 4 + e0];
        const float v = fmaxf(acc[i][j][r] + bias, 0.f) * g;
        ehg[(size_t)(mb + r) * K2_ + n] = f2bf(v);
      }
    }
  }
}

// ---------------- moe2: ym = ehg @ w2t^T + sum_e g*b2, bf16 MFMA, 3-buf 1-barrier (r13) ----------------
__global__ __launch_bounds__(256) void k_moe2_mfma(const short* __restrict__ Aeh,
                                                   const short* __restrict__ Bw,
                                                   const float* __restrict__ b2,
                                                   const float* __restrict__ gates,
                                                   float* __restrict__ ym) {
  __shared__ __align__(16) char lds[3][16384];
  const int tid = threadIdx.x, w = tid >> 6, l = tid & 63;
  const int flat = blockIdx.x + blockIdx.y * 8;            // 512 blocks
  const int swz = (flat & 7) * 64 + (flat >> 3);
  const int n0 = (swz & 7) * 128, m0 = (swz >> 3) * 128;
  const int wr = w >> 1, wc = w & 1, lg = l >> 4, lr = l & 15;
  f32x4 acc[4][4] = {};
  const int sg = tid >> 7, sr = tid & 127;
  const size_t ga0 = (size_t)(m0 + sr) * K2_ + sg * 8;
  const size_t gb0 = (size_t)(n0 + sr) * K2_ + sg * 8;

  auto STAGE = [&](int buf, int k0) {
    char* b = &lds[buf][0] + w * 1024;
    gl_lds16(Aeh + ga0 + k0, b);
    gl_lds16(Aeh + ga0 + 16 + k0, b + 4096);
    gl_lds16(Bw + gb0 + k0, b + 8192);
    gl_lds16(Bw + gb0 + 16 + k0, b + 12288);
  };

  STAGE(0, 0);
  STAGE(1, 32);
  for (int it = 0; it < 64; ++it) {
    const int cur = it % 3;
    if (it < 63) { WAITV(4); } else { WAITV(0); }
    SBAR;
    __builtin_amdgcn_s_barrier();
    if (it < 62) STAGE((it + 2) % 3, (it + 2) * 32);
    const char* bb = &lds[cur][0];
    bf16x8 af[4], bfr[4];
    #pragma unroll
    for (int i = 0; i < 4; ++i)
      af[i] = *(const bf16x8*)(bb + lg * 2048 + (wr * 64 + i * 16 + lr) * 16);
    #pragma unroll
    for (int j = 0; j < 4; ++j)
      bfr[j] = *(const bf16x8*)(bb + 8192 + lg * 2048 + (wc * 64 + j * 16 + lr) * 16);
    __builtin_amdgcn_s_setprio(1);
    #pragma unroll
    for (int i = 0; i < 4; ++i)
      #pragma unroll
      for (int j = 0; j < 4; ++j)
        acc[i][j] = __builtin_amdgcn_mfma_f32_16x16x32_bf16(af[i], bfr[j], acc[i][j], 0, 0, 0);
    __builtin_amdgcn_s_setprio(0);
  }
  float bb2[4][4];
  #pragma unroll
  for (int j = 0; j < 4; ++j) {
    const int n = n0 + wc * 64 + j * 16 + lr;
    #pragma unroll
    for (int e = 0; e < 4; ++e) bb2[j][e] = b2[e * C_ + n];
  }
  #pragma unroll
  for (int i = 0; i < 4; ++i) {
    const int mb = m0 + wr * 64 + i * 16 + lg * 4;
    #pragma unroll
    for (int r = 0; r < 4; ++r) {
      const float4 g = *(const float4*)(gates + (size_t)(mb + r) * 4);
      #pragma unroll
      for (int j = 0; j < 4; ++j) {
        const int n = n0 + wc * 64 + j * 16 + lr;
        ym[(size_t)(mb + r) * C_ + n] =
            acc[i][j][r] + g.x * bb2[j][0] + g.y * bb2[j][1] + g.z * bb2[j][2] + g.w * bb2[j][3];
      }
    }
  }
}

// ---------------- aux loss (deterministic single-block reduction) ----------------
__global__ __launch_bounds__(256) void k_aux(const float* __restrict__ gates, float* __restrict__ outp) {
  const int t = threadIdx.x;
  float imp[4] = {0, 0, 0, 0}, ld[4] = {0, 0, 0, 0};
  for (int m = t; m < M_; m += 256) {
    const float4 g = *(const float4*)(gates + (size_t)m * 4);
    imp[0] += g.x; imp[1] += g.y; imp[2] += g.z; imp[3] += g.w;
    ld[0] += (g.x > 0.f) ? 1.f : 0.f; ld[1] += (g.y > 0.f) ? 1.f : 0.f;
    ld[2] += (g.z > 0.f) ? 1.f : 0.f; ld[3] += (g.w > 0.f) ? 1.f : 0.f;
  }
  __shared__ float red[8][4];
  const int wv = t >> 6, ln = t & 63;
  #pragma unroll
  for (int e = 0; e < 4; ++e) {
    float a = imp[e], b = ld[e];
    #pragma unroll
    for (int o = 32; o; o >>= 1) { a += __shfl_down(a, o); b += __shfl_down(b, o); }
    if (ln == 0) { red[e][wv] = a; red[4 + e][wv] = b; }
  }
  __syncthreads();
  if (t == 0) {
    float I[4], L[4];
    #pragma unroll
    for (int e = 0; e < 4; ++e) {
      I[e] = red[e][0] + red[e][1] + red[e][2] + red[e][3];
      L[e] = red[4 + e][0] + red[4 + e][1] + red[4 + e][2] + red[4 + e][3];
    }
    const float mi = (I[0] + I[1] + I[2] + I[3]) * 0.25f;
    const float vi = ((I[0] - mi) * (I[0] - mi) + (I[1] - mi) * (I[1] - mi) +
                      (I[2] - mi) * (I[2] - mi) + (I[3] - mi) * (I[3] - mi)) / 3.f;
    const float ml = (L[0] + L[1] + L[2] + L[3]) * 0.25f;
    const float vl = ((L[0] - ml) * (L[0] - ml) + (L[1] - ml) * (L[1] - ml) +
                      (L[2] - ml) * (L[2] - ml) + (L[3] - ml) * (L[3] - ml)) / 3.f;
    *outp = vi / (mi * mi + 1e-10f) + vl / (ml * ml + 1e-10f);
  }
}

// ---------------- final: transpose ym [m,c]->[b,c,n], add z = w0*x+(1-w0)*t ----------------
__global__ __launch_bounds__(256) void k_final(const float* __restrict__ ym,
                                               const float* __restrict__ x, const float* __restrict__ t,
                                               const float* __restrict__ wts0, float* __restrict__ out) {
  __shared__ float tile[64][65];
  const int c0 = blockIdx.x * 64, n0 = blockIdx.y * 64, b = blockIdx.z;
  const int tid = threadIdx.x;
  #pragma unroll
  for (int p = 0; p < 4; ++p) {
    const int f = tid + p * 256;
    const int row = f >> 4, cq = f & 15;
    const float4 v = *(const float4*)(ym + (size_t)(b * N_ + n0 + row) * C_ + c0 + cq * 4);
    tile[row][cq * 4 + 0] = v.x; tile[row][cq * 4 + 1] = v.y;
    tile[row][cq * 4 + 2] = v.z; tile[row][cq * 4 + 3] = v.w;
  }
  __syncthreads();
  #pragma unroll
  for (int p = 0; p < 4; ++p) {
    const int f = tid + p * 256;
    const int cr = f >> 4, nq = f & 15;
    const int c = c0 + cr;
    const float w0 = wts0[b * C_ + c];
    const float w1 = 1.f - w0;
    const size_t idx = (size_t)(b * C_ + c) * N_ + n0 + nq * 4;
    const float4 xv = *(const float4*)(x + idx);
    const float4 tv = *(const float4*)(t + idx);
    float4 o;
    o.x = tile[nq * 4 + 0][cr] + w0 * xv.x + w1 * tv.x;
    o.y = tile[nq * 4 + 1][cr] + w0 * xv.y + w1 * tv.y;
    o.z = tile[nq * 4 + 2][cr] + w0 * xv.z + w1 * tv.z;
    o.w = tile[nq * 4 + 3][cr] + w0 * xv.w + w1 * tv.w;
    *(float4*)(out + idx) = o;
  }
}

extern "C" void kernel_launch(void* const* d_in, const int* in_sizes, int n_in,
                              void* d_out, int out_size, void* d_ws, size_t ws_size,
                              hipStream_t stream) {
  const float* x     = (const float*)d_in[0];
  const float* t     = (const float*)d_in[1];
  const float* fc_w  = (const float*)d_in[2];
  const float* ln_g  = (const float*)d_in[3];
  const float* ln_b  = (const float*)d_in[4];
  const float* f1_w1 = (const float*)d_in[5];
  const float* f1_b1 = (const float*)d_in[6];
  const float* f1_wa = (const float*)d_in[7];
  const float* f1_ba = (const float*)d_in[8];
  const float* f1_wb = (const float*)d_in[9];
  const float* f1_bb = (const float*)d_in[10];
  const float* w_gate = (const float*)d_in[11];
  const float* e_w1  = (const float*)d_in[12];
  const float* e_b1  = (const float*)d_in[13];
  const float* e_w2  = (const float*)d_in[14];
  const float* e_b2  = (const float*)d_in[15];
  const int*   task  = (const int*)d_in[16];
  float* out = (float*)d_out;

  char* ws = (char*)d_ws;
  float*          y     = (float*)ws;
  float*          spart = (float*)ws;                      // 512 KB, dead before fc
  _Float16*       ah    = (_Float16*)(ws + 33554432);
  _Float16*       am    = (_Float16*)(ws + 67108864);
  unsigned short* yf    = (unsigned short*)(ws + 33554432);
  unsigned short* ehg   = (unsigned short*)(ws + 50331648);
  _Float16* wh  = (_Float16*)(ws + 100663296);
  _Float16* wm  = (_Float16*)(ws + 104857600);
  short*    w1t = (short*)(ws + 109051904);
  short*    w2t = (short*)(ws + 113246208);
  float* sbuf  = (float*)(ws + 117440512);
  float* wts0  = (float*)(ws + 117448704);
  float* gates = (float*)(ws + 117456896);

  k_prep_fcw<<<1024, 256, 0, stream>>>(fc_w, wh, wm);
  k_prep_tr<<<dim3(8, 16, 4), 256, 0, stream>>>(e_w1, 524288LL, 512, (unsigned short*)w1t, 524288LL, 1024);
  k_prep_tr<<<dim3(16, 8, 4), 256, 0, stream>>>(e_w2, 524288LL, 1024, (unsigned short*)w2t, 512LL, 2048);
  k_prep_act<<<dim3(16, 64, 2), 256, 0, stream>>>(x, t, ah, am, spart);
  k_reduce2<<<8, 256, 0, stream>>>(spart, sbuf);
  k_se_gate<<<1, 256, 0, stream>>>(sbuf, f1_w1, f1_b1, f1_wa, f1_ba, f1_wb, f1_bb, wts0);
  k_fc_mfma<<<dim3(8, 32), 512, 0, stream>>>(ah, am, wh, wm, y);
  k_ln_topk<<<M_ / 4, 256, 0, stream>>>(y, ln_g, ln_b, w_gate, task, yf, gates);
  k_moe1_mfma<<<dim3(16, 64), 256, 0, stream>>>(yf, w1t, e_b1, gates, ehg);
  k_moe2_mfma<<<dim3(8, 64), 256, 0, stream>>>((const short*)ehg, w2t, e_b2, gates, y);
  k_aux<<<1, 256, 0, stream>>>(gates, out + (size_t)B_ * C_ * N_);
  k_final<<<dim3(C_ / 64, N_ / 64, B_), 256, 0, stream>>>(y, x, t, wts0, out);
}